// Round 2
// 122.849 us; speedup vs baseline: 1.0068x; 1.0068x over previous
//
#include <hip/hip_runtime.h>
#include <float.h>

// VQ-VAE vector quantizer forward, MI355X — bf16 MFMA with exact 3-way split.
// x: [B=32, C=64, H=64, W=64] fp32; emb: [K=512, D=64] fp32.
// out flat (b, h*w, c): out[g*64 + c] = emb[argmin_k ||x_g - emb_k||^2][c].
//
// R9 = R8 + workspace guard. R8's design: split the fp32->3xbf16 emb
// decomposition into a tiny prep kernel that writes d_ws in the exact
// per-lane MFMA B-fragment layout [kt][lvl][ch][lane][8] (192 KB,
// L2-resident) + per-half-row |e|^2 partials (same fmaf chain as R7 ->
// bit-identical distances). Main kernel: no LDS staging, no main-loop
// barriers, no split3 per tile; B-frags stream from L2 with a one-tile
// software prefetch. LDS = 1 KB.
// R8 failed with "container failed twice" — suspected cause: unguarded
// d_ws writes (~207 KB at fixed offsets) when ws_size is small/zero.
// R9 checks ws_size and falls back to the verbatim R7 kernel (123.7 us
// known-good, no workspace) if the workspace is unusable.
//
// Verified layouts (m89/m91/m120): A[m=lane&15][k=quad*8+j],
// B[n=lane&15][k=quad*8+j], D col=lane&15, row=quad*4+reg.

typedef __attribute__((ext_vector_type(8))) short  short8;
typedef __attribute__((ext_vector_type(4))) float  floatx4;

#define HWD 4096
#define CD  64
#define KD  512
#define PT  256    // positions per block
#define KT  128    // emb rows staged per nt (fallback path)
#define ESR 72     // fallback LDS row stride in bf16 elems

// ws layout: bs = 32 kt-tiles x 3072 ushorts ([lvl][ch][lane][8]) = 196608 B,
// + one kt tile (6144 B) of prefetch pad; then esq_p = 1024 floats.
#define KT_USH    3072
#define BS_BYTES  (32 * KT_USH * 2)
#define ESQ_OFF   (BS_BYTES + KT_USH * 2)            // 202752
#define WS_NEEDED (ESQ_OFF + 1024 * (int)sizeof(float))  // 206848

// round-to-nearest-even fp32 -> bf16 (bit-level; inputs are finite)
__device__ inline unsigned short bf16_rne(float v) {
    unsigned int u = __builtin_bit_cast(unsigned int, v);
    u += 0x7fffu + ((u >> 16) & 1u);
    return (unsigned short)(u >> 16);
}
__device__ inline float bf16_val(unsigned short h) {
    return __builtin_bit_cast(float, (unsigned int)h << 16);
}
// exact 3-way split: v = h + m + l + eps, |eps| <= 2^-27 |v|
__device__ inline void split3(float v, unsigned short& h, unsigned short& m,
                              unsigned short& l) {
    h = bf16_rne(v);
    float r1 = v - bf16_val(h);     // exact in fp32
    m = bf16_rne(r1);
    float r2 = r1 - bf16_val(m);    // exact in fp32
    l = bf16_rne(r2);
}

#define MFMA(A, B, C) __builtin_amdgcn_mfma_f32_16x16x32_bf16((A), (B), (C), 0, 0, 0)

// ---- prep: split emb into B-fragment layout + |e|^2 half-row partials ----
// thread t (0..1023): k = t>>1, half = t&1. Same load order / fmaf chain /
// split3 as R7's in-block staging -> bit-identical values.
__global__ void vq_prep(const float* __restrict__ emb,
                        unsigned short* __restrict__ bs,
                        float* __restrict__ esq_p) {
    const int t    = blockIdx.x * blockDim.x + threadIdx.x;  // 0..1023
    const int k    = t >> 1;
    const int half = t & 1;
    const int kt   = k >> 4;
    const int n16  = k & 15;
    const float* eg = emb + (size_t)k * CD + half * 32;
    // base of this (kt, ch=half, n16) within bs, ushort units
    unsigned short* bb = bs + (size_t)kt * KT_USH + half * 512 + n16 * 8;
    float s = 0.f;
    #pragma unroll
    for (int q = 0; q < 8; ++q) {
        float4 ev = *(const float4*)(eg + q * 4);
        float vv[4] = {ev.x, ev.y, ev.z, ev.w};
        #pragma unroll
        for (int i = 0; i < 4; ++i) {
            s = fmaf(vv[i], vv[i], s);
            unsigned short h, m, l;
            split3(vv[i], h, m, l);
            const int c    = half * 32 + q * 4 + i;   // 0..63
            const int quad = (c >> 3) & 3;
            const int j    = c & 7;
            const int off  = quad * 128 + j;          // (quad*16)*8 + j
            bb[off]        = h;                       // lvl 0
            bb[1024 + off] = m;                       // lvl 1
            bb[2048 + off] = l;                       // lvl 2
        }
    }
    esq_p[2 * k + half] = s;
}

// ---- main kernel (workspace path): B-frags streamed from L2 ----
__launch_bounds__(256, 2)
__global__ void vq_mfma_kernel(const float* __restrict__ x,
                               const unsigned short* __restrict__ bs,
                               const float* __restrict__ esq_p,
                               const float* __restrict__ emb,
                               float* __restrict__ out) {
    const int tid  = threadIdx.x;
    const int lane = tid & 63;
    const int wv   = __builtin_amdgcn_readfirstlane(tid >> 6);  // 0..3
    const int n16  = lane & 15;   // m for A, n for B, col for D
    const int quad = lane >> 4;   // k-quad for A/B, row-quad for D

    const int g0 = blockIdx.x << 8;   // 256 positions per block
    const int b  = g0 >> 12;          // 256 | 4096: no b straddle
    const int n0 = g0 & 4095;

    __shared__ int bk_s[PT];

    // ---- A fragments: load x, split to 3 bf16 frags (held whole kernel) ----
    // pos = g0 + wv*64 + mt*16 + n16 ; k(c) = ch*32 + quad*8 + j
    short8 ah[4][2], am[4][2], al[4][2];
    {
        const float* xb = x + (size_t)b * (CD * HWD) + n0 + wv * 64 + n16;
        #pragma unroll
        for (int mt = 0; mt < 4; ++mt)
            #pragma unroll
            for (int ch = 0; ch < 2; ++ch) {
                #pragma unroll
                for (int j = 0; j < 8; ++j) {
                    float v = xb[(size_t)(ch * 32 + quad * 8 + j) * HWD + mt * 16];
                    unsigned short h, m, l;
                    split3(v, h, m, l);
                    ah[mt][ch][j] = (short)h;
                    am[mt][ch][j] = (short)m;
                    al[mt][ch][j] = (short)l;
                }
            }
    }

    float bestd[16]; int bestk[16];
    #pragma unroll
    for (int i = 0; i < 16; ++i) { bestd[i] = FLT_MAX; bestk[i] = 0; }

    // ---- main loop: 32 k-tiles of 16 codes, B-frags streamed from L2 ----
    // per-lane frag i (= lvl*2 + ch) of tile kt lives at short8 index
    // kt*384 + i*64 + lane  (ushort kt*3072 + i*512 + lane*8).
    const short8* bp = (const short8*)bs + lane;
    short8 f[6];
    #pragma unroll
    for (int i = 0; i < 6; ++i) f[i] = bp[i * 64];

    for (int kt = 0; kt < 32; ++kt) {
        // prefetch next tile (kt=31 reads the 6 KB pad; values unused)
        short8 g[6];
        #pragma unroll
        for (int i = 0; i < 6; ++i) g[i] = bp[384 + i * 64];

        const int kv = (kt << 4) + n16;            // this lane's code col
        const float2 ep = *(const float2*)&esq_p[2 * kv];
        const float eq = ep.x + ep.y;              // same assoc as R7

        floatx4 acc[4];
        #pragma unroll
        for (int mt = 0; mt < 4; ++mt) acc[mt] = (floatx4){0.f, 0.f, 0.f, 0.f};

        // small -> large accumulation; mt-inner gives 4-way MFMA ILP
        // f[0],f[1]=e_h  f[2],f[3]=e_m  f[4],f[5]=e_l  (ch 0/1 each)
        #define STEP(AR, B0, B1)                                              \
            { _Pragma("unroll")                                               \
              for (int mt = 0; mt < 4; ++mt) acc[mt] = MFMA(AR[mt][0], B0, acc[mt]); \
              _Pragma("unroll")                                               \
              for (int mt = 0; mt < 4; ++mt) acc[mt] = MFMA(AR[mt][1], B1, acc[mt]); }
        STEP(al, f[0], f[1])   // x_l * e_h   (~2^-18)
        STEP(am, f[2], f[3])   // x_m * e_m   (~2^-18)
        STEP(ah, f[4], f[5])   // x_h * e_l   (~2^-18)
        STEP(am, f[0], f[1])   // x_m * e_h   (~2^-9)
        STEP(ah, f[2], f[3])   // x_h * e_m   (~2^-9)
        STEP(ah, f[0], f[1])   // x_h * e_h   (O(1))
        #undef STEP

        // distances + running argmin (k ascending: strict < keeps lowest k)
        #pragma unroll
        for (int mt = 0; mt < 4; ++mt)
            #pragma unroll
            for (int r = 0; r < 4; ++r) {
                float d = fmaf(-2.f, acc[mt][r], eq);
                int idx = mt * 4 + r;
                if (d < bestd[idx]) { bestd[idx] = d; bestk[idx] = kv; }
            }

        #pragma unroll
        for (int i = 0; i < 6; ++i) f[i] = g[i];
        bp += 384;
    }

    // ---- cross-lane argmin over the 16 code-columns (lane bits 0..3) ----
    #pragma unroll
    for (int msk = 1; msk <= 8; msk <<= 1)
        #pragma unroll
        for (int i = 0; i < 16; ++i) {
            float od = __shfl_xor(bestd[i], msk, 64);
            int   ok = __shfl_xor(bestk[i], msk, 64);
            bool take = (od < bestd[i]) || (od == bestd[i] && ok < bestk[i]);
            if (take) { bestd[i] = od; bestk[i] = ok; }
        }
    // D row = quad*4 + r within tile -> pos = wv*64 + mt*16 + quad*4 + r
    if (n16 == 0) {
        #pragma unroll
        for (int mt = 0; mt < 4; ++mt)
            #pragma unroll
            for (int r = 0; r < 4; ++r)
                bk_s[wv * 64 + mt * 16 + quad * 4 + r] = bestk[mt * 4 + r];
    }
    __syncthreads();

    // ---- gather epilogue: wave-uniform rows, 256-B coalesced, batched ----
    const size_t ob = (size_t)g0 * CD;
    for (int it = 0; it < 16; ++it) {
        float v[4]; int pp[4];
        #pragma unroll
        for (int j = 0; j < 4; ++j) {
            int p = (it * 4 + j) * 4 + wv;
            pp[j] = p;
            v[j]  = emb[bk_s[p] * CD + lane];   // L2-hot fp32 row
        }
        #pragma unroll
        for (int j = 0; j < 4; ++j)
            out[ob + (size_t)pp[j] * CD + lane] = v[j];
    }
}

// ---- fallback (no workspace): verbatim R7 kernel, 123.7 us known-good ----
__launch_bounds__(256, 2)
__global__ void vq_mfma_fb(const float* __restrict__ x,
                           const float* __restrict__ emb,
                           float* __restrict__ out) {
    const int tid  = threadIdx.x;
    const int lane = tid & 63;
    const int wv   = __builtin_amdgcn_readfirstlane(tid >> 6);  // 0..3
    const int n16  = lane & 15;
    const int quad = lane >> 4;

    const int g0 = blockIdx.x << 8;
    const int b  = g0 >> 12;
    const int n0 = g0 & 4095;

    __shared__ unsigned short es_h[KT][ESR];
    __shared__ unsigned short es_m[KT][ESR];
    __shared__ unsigned short es_l[KT][ESR];
    __shared__ float esq_p[2 * KT];
    __shared__ int   bk_s[PT];

    short8 ah[4][2], am[4][2], al[4][2];
    {
        const float* xb = x + (size_t)b * (CD * HWD) + n0 + wv * 64 + n16;
        #pragma unroll
        for (int mt = 0; mt < 4; ++mt)
            #pragma unroll
            for (int ch = 0; ch < 2; ++ch) {
                #pragma unroll
                for (int j = 0; j < 8; ++j) {
                    float v = xb[(size_t)(ch * 32 + quad * 8 + j) * HWD + mt * 16];
                    unsigned short h, m, l;
                    split3(v, h, m, l);
                    ah[mt][ch][j] = (short)h;
                    am[mt][ch][j] = (short)m;
                    al[mt][ch][j] = (short)l;
                }
            }
    }

    float bestd[16]; int bestk[16];
    #pragma unroll
    for (int i = 0; i < 16; ++i) { bestd[i] = FLT_MAX; bestk[i] = 0; }

    const int lr   = tid >> 1;
    const int half = tid & 1;

    for (int nt = 0; nt < KD / KT; ++nt) {
        __syncthreads();
        {
            const float* eg = emb + (size_t)(nt * KT + lr) * CD + half * 32;
            float s = 0.f;
            #pragma unroll
            for (int q = 0; q < 8; ++q) {
                float4 ev = *(const float4*)(eg + q * 4);
                float vv[4] = {ev.x, ev.y, ev.z, ev.w};
                ushort4 h4, m4, l4;
                unsigned short* hp = (unsigned short*)&h4;
                unsigned short* mp = (unsigned short*)&m4;
                unsigned short* lp = (unsigned short*)&l4;
                #pragma unroll
                for (int i = 0; i < 4; ++i) {
                    s = fmaf(vv[i], vv[i], s);
                    split3(vv[i], hp[i], mp[i], lp[i]);
                }
                int c0 = half * 32 + q * 4;
                *(ushort4*)&es_h[lr][c0] = h4;
                *(ushort4*)&es_m[lr][c0] = m4;
                *(ushort4*)&es_l[lr][c0] = l4;
            }
            esq_p[2 * lr + half] = s;
        }
        __syncthreads();

        #pragma unroll 2
        for (int ln = 0; ln < 8; ++ln) {
            const int krow = ln * 16 + n16;
            const unsigned short* ph = &es_h[krow][quad * 8];
            const unsigned short* pm = &es_m[krow][quad * 8];
            const unsigned short* pl = &es_l[krow][quad * 8];
            short8 bh0 = *(const short8*)ph,  bh1 = *(const short8*)(ph + 32);
            short8 bm0 = *(const short8*)pm,  bm1 = *(const short8*)(pm + 32);
            short8 bl0 = *(const short8*)pl,  bl1 = *(const short8*)(pl + 32);
            const float eq = esq_p[2 * krow] + esq_p[2 * krow + 1];
            const int   kv = nt * KT + ln * 16 + n16;

            floatx4 acc[4];
            #pragma unroll
            for (int mt = 0; mt < 4; ++mt) acc[mt] = (floatx4){0.f, 0.f, 0.f, 0.f};

            #define STEPF(AR, B0, B1)                                         \
                { _Pragma("unroll")                                           \
                  for (int mt = 0; mt < 4; ++mt) acc[mt] = MFMA(AR[mt][0], B0, acc[mt]); \
                  _Pragma("unroll")                                           \
                  for (int mt = 0; mt < 4; ++mt) acc[mt] = MFMA(AR[mt][1], B1, acc[mt]); }
            STEPF(al, bh0, bh1)
            STEPF(am, bm0, bm1)
            STEPF(ah, bl0, bl1)
            STEPF(am, bh0, bh1)
            STEPF(ah, bm0, bm1)
            STEPF(ah, bh0, bh1)
            #undef STEPF

            #pragma unroll
            for (int mt = 0; mt < 4; ++mt)
                #pragma unroll
                for (int r = 0; r < 4; ++r) {
                    float d = fmaf(-2.f, acc[mt][r], eq);
                    int idx = mt * 4 + r;
                    if (d < bestd[idx]) { bestd[idx] = d; bestk[idx] = kv; }
                }
        }
    }

    #pragma unroll
    for (int msk = 1; msk <= 8; msk <<= 1)
        #pragma unroll
        for (int i = 0; i < 16; ++i) {
            float od = __shfl_xor(bestd[i], msk, 64);
            int   ok = __shfl_xor(bestk[i], msk, 64);
            bool take = (od < bestd[i]) || (od == bestd[i] && ok < bestk[i]);
            if (take) { bestd[i] = od; bestk[i] = ok; }
        }
    if (n16 == 0) {
        #pragma unroll
        for (int mt = 0; mt < 4; ++mt)
            #pragma unroll
            for (int r = 0; r < 4; ++r)
                bk_s[wv * 64 + mt * 16 + quad * 4 + r] = bestk[mt * 4 + r];
    }
    __syncthreads();

    const size_t ob = (size_t)g0 * CD;
    for (int it = 0; it < 16; ++it) {
        float v[4]; int pp[4];
        #pragma unroll
        for (int j = 0; j < 4; ++j) {
            int p = (it * 4 + j) * 4 + wv;
            pp[j] = p;
            v[j]  = emb[bk_s[p] * CD + lane];
        }
        #pragma unroll
        for (int j = 0; j < 4; ++j)
            out[ob + (size_t)pp[j] * CD + lane] = v[j];
    }
}

extern "C" void kernel_launch(void* const* d_in, const int* in_sizes, int n_in,
                              void* d_out, int out_size, void* d_ws, size_t ws_size,
                              hipStream_t stream) {
    const float* x   = (const float*)d_in[0];   // 32*64*64*64
    const float* emb = (const float*)d_in[1];   // 512*64
    float* out = (float*)d_out;                 // 8388608 floats

    if (d_ws != nullptr && ws_size >= (size_t)WS_NEEDED) {
        unsigned short* bs = (unsigned short*)d_ws;       // 196608 B + 6 KB pad
        float* esq_p = (float*)((char*)d_ws + ESQ_OFF);   // 1024 floats
        vq_prep<<<16, 64, 0, stream>>>(emb, bs, esq_p);
        vq_mfma_kernel<<<512, 256, 0, stream>>>(x, bs, esq_p, emb, out);
    } else {
        vq_mfma_fb<<<512, 256, 0, stream>>>(x, emb, out);
    }
}